// Round 1
// baseline (1576.965 us; speedup 1.0000x reference)
//
#include <hip/hip_runtime.h>

constexpr int B = 4, C = 256, H = 64, W = 64, HW = 4096;
constexpr int K2 = 9;
constexpr int OFFC = 18; // 2*K2
constexpr int CHUNK = 32;

// ---------------- offset conv: 3x3, C=256 -> 18, pad 1 ----------------
__global__ void offset_conv_k(const float* __restrict__ x, const float* __restrict__ ow,
                              const float* __restrict__ ob, float* __restrict__ off) {
  int tid = blockIdx.x * 256 + threadIdx.x;   // tid = ((b*18 + oc)*64 + i)*64 + j
  int j  = tid & 63;
  int i  = (tid >> 6) & 63;
  int oc = (tid >> 12) % OFFC;
  int b  = tid / (OFFC * HW);
  const float* xb = x + (size_t)b * C * HW;
  float acc = ob[oc];
  for (int c = 0; c < C; ++c) {
    const float* xc = xb + (size_t)c * HW;
    const float* wr = ow + ((size_t)oc * C + c) * 9;
#pragma unroll
    for (int ky = 0; ky < 3; ++ky) {
      int yy = i + ky - 1;
      if (yy < 0 || yy >= H) continue;
      const float* row = xc + yy * W;
#pragma unroll
      for (int kx = 0; kx < 3; ++kx) {
        int xx = j + kx - 1;
        if (xx >= 0 && xx < W) acc += row[xx] * wr[ky * 3 + kx];
      }
    }
  }
  off[tid] = acc;
}

// ---------------- fused deformable conv + bias + GN partial stats ----------------
__launch_bounds__(512)
__global__ void deform_conv_k(const float* __restrict__ xin, const float* __restrict__ off,
                              const float* __restrict__ w, const float* __restrict__ bias,
                              float* __restrict__ y, float* __restrict__ stats) {
  int b = blockIdx.x >> 6;   // grid = B*H = 256 blocks
  int i = blockIdx.x & 63;
  int t = threadIdx.x;       // 512 threads

  __shared__ float s_w00[K2][64], s_w01[K2][64], s_w10[K2][64], s_w11[K2][64];
  __shared__ int   s_i00[K2][64], s_i01[K2][64], s_i10[K2][64], s_i11[K2][64];
  __shared__ float s_s[CHUNK][K2][64];          // 73728 B sampled tile
  __shared__ float rs_[8], rq_[8];

  const float* xb = xin + (size_t)b * C * HW;

  // Phase A: bilinear metadata for 9 taps x 64 pixels of row i
  for (int idx = t; idx < K2 * 64; idx += 512) {
    int k = idx >> 6, j = idx & 63;
    float dy = off[((size_t)(b * OFFC + 2 * k)     << 12) + (i << 6) + j];
    float dx = off[((size_t)(b * OFFC + 2 * k + 1) << 12) + (i << 6) + j];
    float py = (float)(i + (k / 3) - 1) + dy;
    float px = (float)(j + (k % 3) - 1) + dx;
    float y0f = floorf(py), x0f = floorf(px);
    float wy1 = py - y0f, wx1 = px - x0f;
    float wy0 = 1.f - wy1, wx0 = 1.f - wx1;
    int y0 = (int)y0f, x0 = (int)x0f;
    if (!(y0 >= 0 && y0 < H))         wy0 = 0.f;
    if (!(y0 + 1 >= 0 && y0 + 1 < H)) wy1 = 0.f;
    if (!(x0 >= 0 && x0 < W))         wx0 = 0.f;
    if (!(x0 + 1 >= 0 && x0 + 1 < W)) wx1 = 0.f;
    int y0c = min(max(y0, 0), H - 1), y1c = min(max(y0 + 1, 0), H - 1);
    int x0c = min(max(x0, 0), W - 1), x1c = min(max(x0 + 1, 0), W - 1);
    s_w00[k][j] = wy0 * wx0; s_w01[k][j] = wy0 * wx1;
    s_w10[k][j] = wy1 * wx0; s_w11[k][j] = wy1 * wx1;
    s_i00[k][j] = y0c * W + x0c; s_i01[k][j] = y0c * W + x1c;
    s_i10[k][j] = y1c * W + x0c; s_i11[k][j] = y1c * W + x1c;
  }
  __syncthreads();

  float acc[32];
#pragma unroll
  for (int q = 0; q < 32; ++q) acc[q] = 0.f;
  int o  = t & 255;
  int jh = t >> 8;            // 0/1: which half of the 64-pixel row

  for (int cb = 0; cb < C; cb += CHUNK) {
    // Phase B: gather+interpolate sampled[cc][k][j] for 32 channels
    {
      int j  = t & 63;
      int cg = t >> 6;        // 0..7, each covers 4 channels
#pragma unroll
      for (int k = 0; k < K2; ++k) {
        float w00 = s_w00[k][j], w01 = s_w01[k][j];
        float w10 = s_w10[k][j], w11 = s_w11[k][j];
        int i00 = s_i00[k][j], i01 = s_i01[k][j];
        int i10 = s_i10[k][j], i11 = s_i11[k][j];
#pragma unroll
        for (int cs = 0; cs < CHUNK / 8; ++cs) {
          int cc = cg * (CHUNK / 8) + cs;
          const float* xc = xb + (size_t)(cb + cc) * HW;
          s_s[cc][k][j] = w00 * xc[i00] + w01 * xc[i01] + w10 * xc[i10] + w11 * xc[i11];
        }
      }
    }
    __syncthreads();
    // Phase C: GEMM fragment, thread-per-o, LDS broadcast reads
    const float* wbase = w + ((size_t)o * C + cb) * 9;
    for (int cc = 0; cc < CHUNK; ++cc) {
      const float* wr = wbase + cc * 9;
#pragma unroll
      for (int k = 0; k < K2; ++k) {
        float wv = wr[k];
        const float* sr = &s_s[cc][k][jh * 32];
#pragma unroll
        for (int q = 0; q < 32; ++q) acc[q] += sr[q] * wv;
      }
    }
    __syncthreads();
  }

  // epilogue: bias, store, GN partial stats
  float bv = bias[o];
  float psum = 0.f, psq = 0.f;
  float* yp = y + ((size_t)(b * C + o)) * HW + (i << 6) + jh * 32;
#pragma unroll
  for (int q = 0; q < 32; ++q) {
    float v = acc[q] + bv;
    yp[q] = v;
    psum += v;
    psq  += v * v;
  }
#pragma unroll
  for (int d = 32; d > 0; d >>= 1) {
    psum += __shfl_down(psum, d);
    psq  += __shfl_down(psq, d);
  }
  int wid = t >> 6, lane = t & 63;
  if (lane == 0) { rs_[wid] = psum; rq_[wid] = psq; }
  __syncthreads();
  if (t == 0) {
    float a = 0.f, s2 = 0.f;
    for (int u = 0; u < 8; ++u) { a += rs_[u]; s2 += rq_[u]; }
    atomicAdd(&stats[b * 2],     a);
    atomicAdd(&stats[b * 2 + 1], s2);
  }
}

// ---------------- group-norm (per-sample, all C,H,W) + optional relu ----------------
__global__ void gn_k(const float* __restrict__ yv, const float* __restrict__ stats,
                     const float* __restrict__ g, const float* __restrict__ be,
                     float* __restrict__ outp, int relu) {
  const float inv = 1.f / (float)(C * HW);
  int stride = gridDim.x * blockDim.x;
  int total4 = B * C * HW / 4;
  for (int idx = blockIdx.x * blockDim.x + threadIdx.x; idx < total4; idx += stride) {
    int e = idx << 2;
    int b = e >> 20;
    int c = (e >> 12) & 255;
    float mean = stats[b * 2] * inv;
    float var  = stats[b * 2 + 1] * inv - mean * mean;
    float rs   = rsqrtf(var + 1e-5f);
    float a  = g[c] * rs;
    float b2 = be[c] - mean * a;
    float4 v = *reinterpret_cast<const float4*>(yv + e);
    float4 r;
    r.x = v.x * a + b2; r.y = v.y * a + b2; r.z = v.z * a + b2; r.w = v.w * a + b2;
    if (relu) {
      r.x = fmaxf(0.f, r.x); r.y = fmaxf(0.f, r.y);
      r.z = fmaxf(0.f, r.z); r.w = fmaxf(0.f, r.w);
    }
    *reinterpret_cast<float4*>(outp + e) = r;
  }
}

// ---------------- residual add + GN partial stats ----------------
__global__ void res_stats_k(const float* __restrict__ h2, const float* __restrict__ x,
                            float* __restrict__ z, float* __restrict__ stats) {
  int b = blockIdx.x >> 8;    // grid = B*256
  int seg = blockIdx.x & 255;
  size_t base = ((size_t)b << 20) + ((size_t)seg << 12);
  int t = threadIdx.x;
  float psum = 0.f, psq = 0.f;
#pragma unroll
  for (int u = 0; u < 4; ++u) {
    size_t e = base + (size_t)(u * 256 + t) * 4;
    float4 a = *reinterpret_cast<const float4*>(h2 + e);
    float4 c = *reinterpret_cast<const float4*>(x + e);
    float4 r = make_float4(a.x + c.x, a.y + c.y, a.z + c.z, a.w + c.w);
    *reinterpret_cast<float4*>(z + e) = r;
    psum += r.x + r.y + r.z + r.w;
    psq  += r.x * r.x + r.y * r.y + r.z * r.z + r.w * r.w;
  }
#pragma unroll
  for (int d = 32; d > 0; d >>= 1) {
    psum += __shfl_down(psum, d);
    psq  += __shfl_down(psq, d);
  }
  __shared__ float rs_[4], rq_[4];
  int wid = t >> 6, lane = t & 63;
  if (lane == 0) { rs_[wid] = psum; rq_[wid] = psq; }
  __syncthreads();
  if (t == 0) {
    float a = 0.f, s2 = 0.f;
    for (int u = 0; u < 4; ++u) { a += rs_[u]; s2 += rq_[u]; }
    atomicAdd(&stats[b * 2],     a);
    atomicAdd(&stats[b * 2 + 1], s2);
  }
}

extern "C" void kernel_launch(void* const* d_in, const int* in_sizes, int n_in,
                              void* d_out, int out_size, void* d_ws, size_t ws_size,
                              hipStream_t stream) {
  const float* x   = (const float*)d_in[0];
  const float* ow1 = (const float*)d_in[1];
  const float* ob1 = (const float*)d_in[2];
  const float* dw1 = (const float*)d_in[3];
  const float* db1 = (const float*)d_in[4];
  const float* g1  = (const float*)d_in[5];
  const float* b1  = (const float*)d_in[6];
  const float* ow2 = (const float*)d_in[7];
  const float* ob2 = (const float*)d_in[8];
  const float* dw2 = (const float*)d_in[9];
  const float* db2 = (const float*)d_in[10];
  const float* g2  = (const float*)d_in[11];
  const float* b2  = (const float*)d_in[12];
  const float* g3  = (const float*)d_in[13];
  const float* b3  = (const float*)d_in[14];

  float* ws  = (float*)d_ws;
  float* off = ws;                                  // B*18*HW = 294912 floats
  float* yb  = ws + 294912;                         // B*C*HW  = 4194304 floats
  float* hb  = ws + 294912 + 4194304;               // B*C*HW
  float* st  = ws + 294912 + 2 * 4194304;           // 24 floats: 3 ops x B x {sum,sumsq}
  float* outp = (float*)d_out;

  hipMemsetAsync(st, 0, 24 * sizeof(float), stream);

  // layer 1
  offset_conv_k<<<1152, 256, 0, stream>>>(x, ow1, ob1, off);
  deform_conv_k<<<256, 512, 0, stream>>>(x, off, dw1, db1, yb, st + 0);
  gn_k<<<2048, 256, 0, stream>>>(yb, st + 0, g1, b1, hb, 1);
  // layer 2
  offset_conv_k<<<1152, 256, 0, stream>>>(hb, ow2, ob2, off);
  deform_conv_k<<<256, 512, 0, stream>>>(hb, off, dw2, db2, yb, st + 8);
  gn_k<<<2048, 256, 0, stream>>>(yb, st + 8, g2, b2, hb, 1);
  // residual + final GN
  res_stats_k<<<1024, 256, 0, stream>>>(hb, x, yb, st + 16);
  gn_k<<<2048, 256, 0, stream>>>(yb, st + 16, g3, b3, outp, 0);
}

// Round 2
// 788.260 us; speedup vs baseline: 2.0006x; 2.0006x over previous
//
#include <hip/hip_runtime.h>

constexpr int B = 4, C = 256, H = 64, W = 64, HW = 4096;
constexpr int K2 = 9, OFFC = 18;
constexpr int SSTR = 296;           // bf16 elements per sampled-LDS row (592 B = 37*16)

typedef short s16x8 __attribute__((ext_vector_type(8)));
typedef float f32x4 __attribute__((ext_vector_type(4)));

__device__ __forceinline__ unsigned short f2bf(float f) {
  unsigned u = __float_as_uint(f);
  u += 0x7fffu + ((u >> 16) & 1u);          // round-to-nearest-even
  return (unsigned short)(u >> 16);
}

// ---------------- fp32 -> bf16 weight conversion ----------------
__global__ void cvt_bf16_k(const float* __restrict__ src, unsigned short* __restrict__ dst, int n4) {
  int idx = blockIdx.x * 256 + threadIdx.x;
  if (idx >= n4) return;
  float4 v = reinterpret_cast<const float4*>(src)[idx];
  ushort4 o;
  o.x = f2bf(v.x); o.y = f2bf(v.y); o.z = f2bf(v.z); o.w = f2bf(v.w);
  reinterpret_cast<ushort4*>(dst)[idx] = o;
}

// ---------------- offset conv: 3x3, C=256 -> 18, pad 1 (LDS-staged fp32) ----------------
__launch_bounds__(256)
__global__ void offset_conv_k(const float* __restrict__ x, const float* __restrict__ ow,
                              const float* __restrict__ ob, float* __restrict__ off) {
  int b = blockIdx.x >> 6, i = blockIdx.x & 63;
  int t = threadIdx.x;
  int j = t & 63, ocg = t >> 6;          // wave-uniform ocg -> broadcast weight reads
  __shared__ float xs[32][3][66];        // 32 channels x 3 rows x (64+2 halo)
  __shared__ float ws_[OFFC][32][9];
  const float* xb = x + (size_t)b * C * HW;

  if (t < 96) { int cc = t & 31, rr = t >> 5; xs[cc][rr][0] = 0.f; xs[cc][rr][65] = 0.f; }

  float acc[5];
#pragma unroll
  for (int s = 0; s < 5; ++s) {
    int oc = ocg + 4 * s;
    acc[s] = (oc < OFFC) ? ob[oc] : 0.f;
  }

  for (int cb = 0; cb < C; cb += 32) {
    for (int idx = t; idx < 32 * 3 * 64; idx += 256) {
      int j2 = idx & 63, rr = (idx >> 6) % 3, cc = idx / 192;
      int yy = i + rr - 1;
      xs[cc][rr][1 + j2] = (yy >= 0 && yy < H) ? xb[(size_t)(cb + cc) * HW + yy * 64 + j2] : 0.f;
    }
    for (int idx = t; idx < OFFC * 32 * 9; idx += 256) {
      int k = idx % 9, cc = (idx / 9) % 32, oc = idx / 288;
      ws_[oc][cc][k] = ow[((size_t)oc * C + cb + cc) * 9 + k];
    }
    __syncthreads();
    for (int cc = 0; cc < 32; ++cc) {
      float xv[9];
#pragma unroll
      for (int rr = 0; rr < 3; ++rr)
#pragma unroll
        for (int dx = 0; dx < 3; ++dx) xv[rr * 3 + dx] = xs[cc][rr][j + dx];
#pragma unroll
      for (int s = 0; s < 5; ++s) {
        int oc = ocg + 4 * s;
        if (oc < OFFC) {
          const float* wp = &ws_[oc][cc][0];
#pragma unroll
          for (int k = 0; k < 9; ++k) acc[s] += xv[k] * wp[k];
        }
      }
    }
    __syncthreads();
  }
#pragma unroll
  for (int s = 0; s < 5; ++s) {
    int oc = ocg + 4 * s;
    if (oc < OFFC) off[((size_t)(b * OFFC + oc) << 12) + (i << 6) + j] = acc[s];
  }
}

// ---------------- fused deformable conv (bf16 MFMA) + bias + GN partial stats ----------------
// block = (b, i): GEMM  out[64 px][256 o] = sampled[64][2304] x W^T[2304][256]
__launch_bounds__(512)
__global__ void deform_mfma_k(const float* __restrict__ xin, const float* __restrict__ off,
                              const unsigned short* __restrict__ wbf,
                              const float* __restrict__ bias,
                              float* __restrict__ y, float* __restrict__ stats) {
  int b = blockIdx.x >> 6, i = blockIdx.x & 63;
  int t = threadIdx.x;
  int lane = t & 63, wv = t >> 6;        // 8 waves
  int cidx = lane & 15, r = lane >> 4;   // MFMA lane decomposition

  __shared__ float s_wt[4][K2][64];
  __shared__ int   s_ix[4][K2][64];
  __shared__ __align__(16) unsigned short s_s[2][64][SSTR];   // double-buffered sampled tile
  __shared__ float rs_[8], rq_[8];

  const float* xb = xin + (size_t)b * C * HW;

  // Phase A: bilinear metadata for 9 taps x 64 pixels of row i (chunk-independent)
  for (int idx = t; idx < K2 * 64; idx += 512) {
    int k = idx >> 6, j = idx & 63;
    float dy = off[((size_t)(b * OFFC + 2 * k) << 12) + (i << 6) + j];
    float dx = off[((size_t)(b * OFFC + 2 * k + 1) << 12) + (i << 6) + j];
    float py = (float)(i + (k / 3) - 1) + dy;
    float px = (float)(j + (k % 3) - 1) + dx;
    float y0f = floorf(py), x0f = floorf(px);
    float wy1 = py - y0f, wx1 = px - x0f;
    float wy0 = 1.f - wy1, wx0 = 1.f - wx1;
    int y0 = (int)y0f, x0 = (int)x0f;
    if (y0 < 0 || y0 >= H)         wy0 = 0.f;
    if (y0 + 1 < 0 || y0 + 1 >= H) wy1 = 0.f;
    if (x0 < 0 || x0 >= W)         wx0 = 0.f;
    if (x0 + 1 < 0 || x0 + 1 >= W) wx1 = 0.f;
    int y0c = min(max(y0, 0), H - 1), y1c = min(max(y0 + 1, 0), H - 1);
    int x0c = min(max(x0, 0), W - 1), x1c = min(max(x0 + 1, 0), W - 1);
    s_wt[0][k][j] = wy0 * wx0; s_wt[1][k][j] = wy0 * wx1;
    s_wt[2][k][j] = wy1 * wx0; s_wt[3][k][j] = wy1 * wx1;
    s_ix[0][k][j] = y0c * W + x0c; s_ix[1][k][j] = y0c * W + x1c;
    s_ix[2][k][j] = y1c * W + x0c; s_ix[3][k][j] = y1c * W + x1c;
  }
  __syncthreads();

  // Phase B: gather+interp 32 channels x 9 taps x 64 px -> bf16 LDS, k-contiguous per px
  auto stageB = [&](int cbi, int bufi) {
    int j = t & 63, g = t >> 6;
    for (int k = 0; k < K2; ++k) {
      float w00 = s_wt[0][k][j], w01 = s_wt[1][k][j];
      float w10 = s_wt[2][k][j], w11 = s_wt[3][k][j];
      int i00 = s_ix[0][k][j], i01 = s_ix[1][k][j];
      int i10 = s_ix[2][k][j], i11 = s_ix[3][k][j];
#pragma unroll
      for (int s = 0; s < 4; ++s) {
        int cc = g * 4 + s;
        const float* xc = xb + (size_t)(cbi * 32 + cc) * HW;
        float v = w00 * xc[i00] + w01 * xc[i01] + w10 * xc[i10] + w11 * xc[i11];
        s_s[bufi][j][cc * 9 + k] = f2bf(v);
      }
    }
  };

  f32x4 acc[4][2];
#pragma unroll
  for (int m = 0; m < 4; ++m) {
    acc[m][0] = {0.f, 0.f, 0.f, 0.f};
    acc[m][1] = {0.f, 0.f, 0.f, 0.f};
  }

  int ob_ = wv * 32;                                   // wave's o-base (2 N-tiles)
  const unsigned short* w0p = wbf + (size_t)(ob_ + cidx) * 2304;
  const unsigned short* w1p = w0p + 16 * 2304;

  stageB(0, 0);
  __syncthreads();

  for (int cbi = 0; cbi < 8; ++cbi) {
    int bufi = cbi & 1;
    if (cbi < 7) stageB(cbi + 1, bufi ^ 1);            // issue gathers before MFMAs
    int kchunk = cbi * 288 + r * 8;
#pragma unroll 3
    for (int kk = 0; kk < 9; ++kk) {
      int kb = kk * 32 + r * 8;
      s16x8 a0 = *(const s16x8*)&s_s[bufi][ 0 + cidx][kb];
      s16x8 a1 = *(const s16x8*)&s_s[bufi][16 + cidx][kb];
      s16x8 a2 = *(const s16x8*)&s_s[bufi][32 + cidx][kb];
      s16x8 a3 = *(const s16x8*)&s_s[bufi][48 + cidx][kb];
      s16x8 b0 = *(const s16x8*)&w0p[kchunk + kk * 32];
      s16x8 b1 = *(const s16x8*)&w1p[kchunk + kk * 32];
      acc[0][0] = __builtin_amdgcn_mfma_f32_16x16x32_bf16(a0, b0, acc[0][0], 0, 0, 0);
      acc[1][0] = __builtin_amdgcn_mfma_f32_16x16x32_bf16(a1, b0, acc[1][0], 0, 0, 0);
      acc[2][0] = __builtin_amdgcn_mfma_f32_16x16x32_bf16(a2, b0, acc[2][0], 0, 0, 0);
      acc[3][0] = __builtin_amdgcn_mfma_f32_16x16x32_bf16(a3, b0, acc[3][0], 0, 0, 0);
      acc[0][1] = __builtin_amdgcn_mfma_f32_16x16x32_bf16(a0, b1, acc[0][1], 0, 0, 0);
      acc[1][1] = __builtin_amdgcn_mfma_f32_16x16x32_bf16(a1, b1, acc[1][1], 0, 0, 0);
      acc[2][1] = __builtin_amdgcn_mfma_f32_16x16x32_bf16(a2, b1, acc[2][1], 0, 0, 0);
      acc[3][1] = __builtin_amdgcn_mfma_f32_16x16x32_bf16(a3, b1, acc[3][1], 0, 0, 0);
    }
    __syncthreads();
  }

  // epilogue: bias, store (full 64B segments per o-row), GN partial stats
  float bv0 = bias[ob_ + cidx], bv1 = bias[ob_ + 16 + cidx];
  float psum = 0.f, psq = 0.f;
#pragma unroll
  for (int m = 0; m < 4; ++m) {
#pragma unroll
    for (int n = 0; n < 2; ++n) {
      int o = ob_ + n * 16 + cidx;
      float bv = n ? bv1 : bv0;
      float4 vv;
      vv.x = acc[m][n][0] + bv; vv.y = acc[m][n][1] + bv;
      vv.z = acc[m][n][2] + bv; vv.w = acc[m][n][3] + bv;
      *reinterpret_cast<float4*>(y + (((size_t)(b * C + o)) << 12) + (i << 6) + m * 16 + r * 4) = vv;
      psum += vv.x + vv.y + vv.z + vv.w;
      psq  += vv.x * vv.x + vv.y * vv.y + vv.z * vv.z + vv.w * vv.w;
    }
  }
#pragma unroll
  for (int d = 32; d > 0; d >>= 1) {
    psum += __shfl_down(psum, d);
    psq  += __shfl_down(psq, d);
  }
  if (lane == 0) { rs_[wv] = psum; rq_[wv] = psq; }
  __syncthreads();
  if (t == 0) {
    float a = 0.f, s2 = 0.f;
    for (int u = 0; u < 8; ++u) { a += rs_[u]; s2 += rq_[u]; }
    atomicAdd(&stats[b * 2],     a);
    atomicAdd(&stats[b * 2 + 1], s2);
  }
}

// ---------------- group-norm (per-sample over C,H,W) + optional relu ----------------
__global__ void gn_k(const float* __restrict__ yv, const float* __restrict__ stats,
                     const float* __restrict__ g, const float* __restrict__ be,
                     float* __restrict__ outp, int relu) {
  const float inv = 1.f / (float)(C * HW);
  int stride = gridDim.x * blockDim.x;
  int total4 = B * C * HW / 4;
  for (int idx = blockIdx.x * blockDim.x + threadIdx.x; idx < total4; idx += stride) {
    int e = idx << 2;
    int b = e >> 20;
    int c = (e >> 12) & 255;
    float mean = stats[b * 2] * inv;
    float var  = stats[b * 2 + 1] * inv - mean * mean;
    float rs   = rsqrtf(var + 1e-5f);
    float a  = g[c] * rs;
    float b2 = be[c] - mean * a;
    float4 v = *reinterpret_cast<const float4*>(yv + e);
    float4 rr;
    rr.x = v.x * a + b2; rr.y = v.y * a + b2; rr.z = v.z * a + b2; rr.w = v.w * a + b2;
    if (relu) {
      rr.x = fmaxf(0.f, rr.x); rr.y = fmaxf(0.f, rr.y);
      rr.z = fmaxf(0.f, rr.z); rr.w = fmaxf(0.f, rr.w);
    }
    *reinterpret_cast<float4*>(outp + e) = rr;
  }
}

// ---------------- residual add + GN partial stats ----------------
__global__ void res_stats_k(const float* __restrict__ h2, const float* __restrict__ x,
                            float* __restrict__ z, float* __restrict__ stats) {
  int b = blockIdx.x >> 8;
  int seg = blockIdx.x & 255;
  size_t base = ((size_t)b << 20) + ((size_t)seg << 12);
  int t = threadIdx.x;
  float psum = 0.f, psq = 0.f;
#pragma unroll
  for (int u = 0; u < 4; ++u) {
    size_t e = base + (size_t)(u * 256 + t) * 4;
    float4 a = *reinterpret_cast<const float4*>(h2 + e);
    float4 c = *reinterpret_cast<const float4*>(x + e);
    float4 rr = make_float4(a.x + c.x, a.y + c.y, a.z + c.z, a.w + c.w);
    *reinterpret_cast<float4*>(z + e) = rr;
    psum += rr.x + rr.y + rr.z + rr.w;
    psq  += rr.x * rr.x + rr.y * rr.y + rr.z * rr.z + rr.w * rr.w;
  }
#pragma unroll
  for (int d = 32; d > 0; d >>= 1) {
    psum += __shfl_down(psum, d);
    psq  += __shfl_down(psq, d);
  }
  __shared__ float rs_[4], rq_[4];
  int wid = t >> 6, lane = t & 63;
  if (lane == 0) { rs_[wid] = psum; rq_[wid] = psq; }
  __syncthreads();
  if (t == 0) {
    float a = 0.f, s2 = 0.f;
    for (int u = 0; u < 4; ++u) { a += rs_[u]; s2 += rq_[u]; }
    atomicAdd(&stats[b * 2],     a);
    atomicAdd(&stats[b * 2 + 1], s2);
  }
}

extern "C" void kernel_launch(void* const* d_in, const int* in_sizes, int n_in,
                              void* d_out, int out_size, void* d_ws, size_t ws_size,
                              hipStream_t stream) {
  const float* x   = (const float*)d_in[0];
  const float* ow1 = (const float*)d_in[1];
  const float* ob1 = (const float*)d_in[2];
  const float* dw1 = (const float*)d_in[3];
  const float* db1 = (const float*)d_in[4];
  const float* g1  = (const float*)d_in[5];
  const float* b1  = (const float*)d_in[6];
  const float* ow2 = (const float*)d_in[7];
  const float* ob2 = (const float*)d_in[8];
  const float* dw2 = (const float*)d_in[9];
  const float* db2 = (const float*)d_in[10];
  const float* g2  = (const float*)d_in[11];
  const float* b2  = (const float*)d_in[12];
  const float* g3  = (const float*)d_in[13];
  const float* b3  = (const float*)d_in[14];

  float* ws  = (float*)d_ws;
  float* off = ws;                                   // B*18*HW          = 294912 f
  float* yb  = ws + 294912;                          // B*C*HW           = 4194304 f
  float* hb  = ws + 294912 + 4194304;                // B*C*HW
  float* st  = ws + 294912 + 2 * 4194304;            // 32 f (3 ops x B x {sum,sumsq})
  unsigned short* wbf1 = (unsigned short*)(ws + 8683552);            // 256*2304 bf16
  unsigned short* wbf2 = (unsigned short*)(ws + 8683552 + 294912);   // 256*2304 bf16
  float* outp = (float*)d_out;

  hipMemsetAsync(st, 0, 32 * sizeof(float), stream);
  cvt_bf16_k<<<576, 256, 0, stream>>>(dw1, wbf1, 147456);
  cvt_bf16_k<<<576, 256, 0, stream>>>(dw2, wbf2, 147456);

  // layer 1
  offset_conv_k<<<256, 256, 0, stream>>>(x, ow1, ob1, off);
  deform_mfma_k<<<256, 512, 0, stream>>>(x, off, wbf1, db1, yb, st + 0);
  gn_k<<<2048, 256, 0, stream>>>(yb, st + 0, g1, b1, hb, 1);
  // layer 2
  offset_conv_k<<<256, 256, 0, stream>>>(hb, ow2, ob2, off);
  deform_mfma_k<<<256, 512, 0, stream>>>(hb, off, wbf2, db2, yb, st + 8);
  gn_k<<<2048, 256, 0, stream>>>(yb, st + 8, g2, b2, hb, 1);
  // residual + final GN
  res_stats_k<<<1024, 256, 0, stream>>>(hb, x, yb, st + 16);
  gn_k<<<2048, 256, 0, stream>>>(yb, st + 16, g3, b3, outp, 0);
}

// Round 4
// 610.955 us; speedup vs baseline: 2.5811x; 1.2902x over previous
//
#include <hip/hip_runtime.h>
#include <hip/hip_fp16.h>

constexpr int B = 4, C = 256, H = 64, W = 64, HW = 4096;
constexpr int K2 = 9, OFFC = 18;
constexpr int SSTR = 296;           // bf16 elements per sampled-LDS row (592 B)

typedef short s16x8 __attribute__((ext_vector_type(8)));
typedef float f32x4 __attribute__((ext_vector_type(4)));

__device__ __forceinline__ unsigned short f2bf(float f) {
  unsigned u = __float_as_uint(f);
  u += 0x7fffu + ((u >> 16) & 1u);          // round-to-nearest-even
  return (unsigned short)(u >> 16);
}

// ---------------- fp32 -> bf16 weight conversion ----------------
__global__ void cvt_bf16_k(const float* __restrict__ src, unsigned short* __restrict__ dst, int n4) {
  int idx = blockIdx.x * 256 + threadIdx.x;
  if (idx >= n4) return;
  float4 v = reinterpret_cast<const float4*>(src)[idx];
  ushort4 o;
  o.x = f2bf(v.x); o.y = f2bf(v.y); o.z = f2bf(v.z); o.w = f2bf(v.w);
  reinterpret_cast<ushort4*>(dst)[idx] = o;
}

// ---------------- offset conv partials: 3x3, 64 channels -> 18, pad 1 ----------------
// grid = B*H*4 : blockIdx = ((b*64 + i)*4 + cq), cq = channel quarter
__launch_bounds__(256)
__global__ void offset_conv_k(const float* __restrict__ x, const float* __restrict__ ow,
                              const float* __restrict__ ob, float* __restrict__ off4) {
  int cq = blockIdx.x & 3;
  int i  = (blockIdx.x >> 2) & 63;
  int b  = blockIdx.x >> 8;
  int t = threadIdx.x;
  int j = t & 63;
  int ocg = __builtin_amdgcn_readfirstlane(t >> 6);   // wave-uniform 0..3
  __shared__ float xs[32][3][66];                      // 32 ch x 3 rows x (64+halo)
  const float* xb = x + (size_t)b * C * HW;

  if (t < 96) { int cc = t & 31, rr = t >> 5; xs[cc][rr][0] = 0.f; xs[cc][rr][65] = 0.f; }

  float acc[5];
#pragma unroll
  for (int s = 0; s < 5; ++s) {
    int oc = ocg + 4 * s;
    acc[s] = (cq == 0 && oc < OFFC) ? ob[oc] : 0.f;
  }

  for (int half = 0; half < 2; ++half) {
    int cbase = cq * 64 + half * 32;
    for (int idx = t; idx < 32 * 192; idx += 256) {
      int cc = idx / 192, rem = idx - cc * 192;
      int rr = rem >> 6, j2 = rem & 63;
      int yy = i + rr - 1;
      xs[cc][rr][1 + j2] = (yy >= 0 && yy < H) ? xb[(size_t)(cbase + cc) * HW + yy * 64 + j2] : 0.f;
    }
    __syncthreads();
    for (int cc = 0; cc < 32; ++cc) {
      float xv[9];
#pragma unroll
      for (int rr = 0; rr < 3; ++rr)
#pragma unroll
        for (int dxx = 0; dxx < 3; ++dxx) xv[rr * 3 + dxx] = xs[cc][rr][j + dxx];
#pragma unroll
      for (int s = 0; s < 5; ++s) {
        int oc = ocg + 4 * s;
        if (oc < OFFC) {
          const float* wp = ow + ((size_t)oc * C + cbase + cc) * 9;   // uniform -> s_load
#pragma unroll
          for (int k = 0; k < 9; ++k) acc[s] += xv[k] * wp[k];
        }
      }
    }
    __syncthreads();
  }
#pragma unroll
  for (int s = 0; s < 5; ++s) {
    int oc = ocg + 4 * s;
    if (oc < OFFC)
      off4[(((size_t)(cq * B + b) * OFFC + oc) << 12) + (i << 6) + j] = acc[s];
  }
}

// ---------------- fused deformable conv (bf16 MFMA) + bias + GN partial stats ----------------
// block = (b, i, half-row): GEMM out[32 px][256 o] = sampled[32][2304] x W^T[2304][256]
__launch_bounds__(512)
__global__ void deform_mfma_k(const float* __restrict__ xin, const float* __restrict__ off4,
                              const unsigned short* __restrict__ wbf,
                              const float* __restrict__ bias,
                              float* __restrict__ y, float* __restrict__ stats) {
  int jh = blockIdx.x & 1;
  int i  = (blockIdx.x >> 1) & 63;
  int b  = blockIdx.x >> 7;
  int t = threadIdx.x;
  int lane = t & 63, wv = t >> 6;        // 8 waves
  int cidx = lane & 15, r = lane >> 4;   // MFMA lane decomposition

  __shared__ __align__(16) unsigned s_md[K2][32][4];          // packed metadata, 4.6 KB
  __shared__ __align__(16) unsigned short s_s[2][32][SSTR];   // dbuf sampled tile, 37.9 KB
  __shared__ float rs_[8], rq_[8];

  const float* xb = xin + (size_t)b * C * HW;

  // Phase A: sum 4 offset partials, build packed bilinear metadata (9 taps x 32 px)
  for (int idx = t; idx < K2 * 32; idx += 512) {
    int k = idx >> 5, jl = idx & 31;
    int j = (jh << 5) + jl;
    float dy = 0.f, dx = 0.f;
#pragma unroll
    for (int cq = 0; cq < 4; ++cq) {
      const float* p = off4 + (((size_t)(cq * B + b) * OFFC) << 12) + (i << 6) + j;
      dy += p[(2 * k) << 12];
      dx += p[(2 * k + 1) << 12];
    }
    float py = (float)(i + (k / 3) - 1) + dy;
    float px = (float)(j + (k % 3) - 1) + dx;
    float y0f = floorf(py), x0f = floorf(px);
    float wy1 = py - y0f, wx1 = px - x0f;
    float wy0 = 1.f - wy1, wx0 = 1.f - wx1;
    int y0 = (int)y0f, x0 = (int)x0f;
    if (y0 < 0 || y0 >= H)         wy0 = 0.f;
    if (y0 + 1 < 0 || y0 + 1 >= H) wy1 = 0.f;
    if (x0 < 0 || x0 >= W)         wx0 = 0.f;
    if (x0 + 1 < 0 || x0 + 1 >= W) wx1 = 0.f;
    int y0c = min(max(y0, 0), H - 1), y1c = min(max(y0 + 1, 0), H - 1);
    int x0c = min(max(x0, 0), W - 1), x1c = min(max(x0 + 1, 0), W - 1);
    unsigned p0 = (unsigned)__half_as_ushort(__float2half_rn(wy0 * wx0)) |
                  ((unsigned)__half_as_ushort(__float2half_rn(wy0 * wx1)) << 16);
    unsigned p1 = (unsigned)__half_as_ushort(__float2half_rn(wy1 * wx0)) |
                  ((unsigned)__half_as_ushort(__float2half_rn(wy1 * wx1)) << 16);
    unsigned i00 = (unsigned)(y0c * W + x0c);
    unsigned dxs = (unsigned)(x1c - x0c), dys = (unsigned)(y1c - y0c);
    unsigned p2 = i00 | (dxs << 12) | (dys << 13);
    *reinterpret_cast<uint4*>(&s_md[k][jl][0]) = make_uint4(p0, p1, p2, 0);
  }
  __syncthreads();

  // Phase B: gather+interp 32 channels x 9 taps x 32 px -> bf16 LDS (k-contig per px)
  auto stageB = [&](int cbi, int bufi) {
    int jl = t & 31, cg = t >> 5;       // cg 0..15, 2 channels each
    const float* xc0 = xb + (size_t)(cbi * 32 + cg * 2) * HW;
    const float* xc1 = xc0 + HW;
    unsigned short* d0 = &s_s[bufi][jl][(cg * 2) * 9];
    unsigned short* d1 = d0 + 9;
#pragma unroll
    for (int k = 0; k < K2; ++k) {
      uint4 m = *reinterpret_cast<const uint4*>(&s_md[k][jl][0]);
      float w00 = __half2float(__ushort_as_half((unsigned short)(m.x & 0xffff)));
      float w01 = __half2float(__ushort_as_half((unsigned short)(m.x >> 16)));
      float w10 = __half2float(__ushort_as_half((unsigned short)(m.y & 0xffff)));
      float w11 = __half2float(__ushort_as_half((unsigned short)(m.y >> 16)));
      int i00 = m.z & 0xfff;
      int dxs = (m.z >> 12) & 1, dys = (m.z >> 13) & 1;
      int i01 = i00 + dxs, i10 = i00 + (dys << 6), i11 = i00 + (dys << 6) + dxs;
      float v0 = w00 * xc0[i00] + w01 * xc0[i01] + w10 * xc0[i10] + w11 * xc0[i11];
      float v1 = w00 * xc1[i00] + w01 * xc1[i01] + w10 * xc1[i10] + w11 * xc1[i11];
      d0[k] = f2bf(v0);
      d1[k] = f2bf(v1);
    }
  };

  f32x4 acc[2][2];
#pragma unroll
  for (int m = 0; m < 2; ++m) {
    acc[m][0] = {0.f, 0.f, 0.f, 0.f};
    acc[m][1] = {0.f, 0.f, 0.f, 0.f};
  }

  int ob_ = wv * 32;
  const unsigned short* w0p = wbf + (size_t)(ob_ + cidx) * 2304;
  const unsigned short* w1p = w0p + 16 * 2304;

  stageB(0, 0);
  __syncthreads();

  for (int cbi = 0; cbi < 8; ++cbi) {
    int bufi = cbi & 1;
    if (cbi < 7) stageB(cbi + 1, bufi ^ 1);       // issue gathers before MFMAs
    int kchunk = cbi * 288 + r * 8;
#pragma unroll 3
    for (int kk = 0; kk < 9; ++kk) {
      int kb = kk * 32 + r * 8;
      s16x8 a0 = *(const s16x8*)&s_s[bufi][cidx][kb];
      s16x8 a1 = *(const s16x8*)&s_s[bufi][16 + cidx][kb];
      s16x8 b0 = *(const s16x8*)&w0p[kchunk + kk * 32];
      s16x8 b1 = *(const s16x8*)&w1p[kchunk + kk * 32];
      acc[0][0] = __builtin_amdgcn_mfma_f32_16x16x32_bf16(a0, b0, acc[0][0], 0, 0, 0);
      acc[1][0] = __builtin_amdgcn_mfma_f32_16x16x32_bf16(a1, b0, acc[1][0], 0, 0, 0);
      acc[0][1] = __builtin_amdgcn_mfma_f32_16x16x32_bf16(a0, b1, acc[0][1], 0, 0, 0);
      acc[1][1] = __builtin_amdgcn_mfma_f32_16x16x32_bf16(a1, b1, acc[1][1], 0, 0, 0);
    }
    __syncthreads();
  }

  // epilogue: bias, store, GN partial stats
  float bv0 = bias[ob_ + cidx], bv1 = bias[ob_ + 16 + cidx];
  float psum = 0.f, psq = 0.f;
#pragma unroll
  for (int m = 0; m < 2; ++m) {
#pragma unroll
    for (int n = 0; n < 2; ++n) {
      int o = ob_ + n * 16 + cidx;
      float bv = n ? bv1 : bv0;
      float4 vv;
      vv.x = acc[m][n][0] + bv; vv.y = acc[m][n][1] + bv;
      vv.z = acc[m][n][2] + bv; vv.w = acc[m][n][3] + bv;
      *reinterpret_cast<float4*>(y + (((size_t)(b * C + o)) << 12) + (i << 6) + (jh << 5) + m * 16 + r * 4) = vv;
      psum += vv.x + vv.y + vv.z + vv.w;
      psq  += vv.x * vv.x + vv.y * vv.y + vv.z * vv.z + vv.w * vv.w;
    }
  }
#pragma unroll
  for (int d = 32; d > 0; d >>= 1) {
    psum += __shfl_down(psum, d);
    psq  += __shfl_down(psq, d);
  }
  if (lane == 0) { rs_[wv] = psum; rq_[wv] = psq; }
  __syncthreads();
  if (t == 0) {
    float a = 0.f, s2 = 0.f;
    for (int u = 0; u < 8; ++u) { a += rs_[u]; s2 += rq_[u]; }
    atomicAdd(&stats[b * 2],     a);
    atomicAdd(&stats[b * 2 + 1], s2);
  }
}

// ---------------- group-norm (per-sample over C,H,W) + optional relu ----------------
__global__ void gn_k(const float* __restrict__ yv, const float* __restrict__ stats,
                     const float* __restrict__ g, const float* __restrict__ be,
                     float* __restrict__ outp, int relu) {
  const float inv = 1.f / (float)(C * HW);
  int stride = gridDim.x * blockDim.x;
  int total4 = B * C * HW / 4;
  for (int idx = blockIdx.x * blockDim.x + threadIdx.x; idx < total4; idx += stride) {
    int e = idx << 2;
    int b = e >> 20;
    int c = (e >> 12) & 255;
    float mean = stats[b * 2] * inv;
    float var  = stats[b * 2 + 1] * inv - mean * mean;
    float rs   = rsqrtf(var + 1e-5f);
    float a  = g[c] * rs;
    float b2 = be[c] - mean * a;
    float4 v = *reinterpret_cast<const float4*>(yv + e);
    float4 rr;
    rr.x = v.x * a + b2; rr.y = v.y * a + b2; rr.z = v.z * a + b2; rr.w = v.w * a + b2;
    if (relu) {
      rr.x = fmaxf(0.f, rr.x); rr.y = fmaxf(0.f, rr.y);
      rr.z = fmaxf(0.f, rr.z); rr.w = fmaxf(0.f, rr.w);
    }
    *reinterpret_cast<float4*>(outp + e) = rr;
  }
}

// ---------------- residual add + GN partial stats ----------------
__global__ void res_stats_k(const float* __restrict__ h2, const float* __restrict__ x,
                            float* __restrict__ z, float* __restrict__ stats) {
  int b = blockIdx.x >> 8;
  int seg = blockIdx.x & 255;
  size_t base = ((size_t)b << 20) + ((size_t)seg << 12);
  int t = threadIdx.x;
  float psum = 0.f, psq = 0.f;
#pragma unroll
  for (int u = 0; u < 4; ++u) {
    size_t e = base + (size_t)(u * 256 + t) * 4;
    float4 a = *reinterpret_cast<const float4*>(h2 + e);
    float4 c = *reinterpret_cast<const float4*>(x + e);
    float4 rr = make_float4(a.x + c.x, a.y + c.y, a.z + c.z, a.w + c.w);
    *reinterpret_cast<float4*>(z + e) = rr;
    psum += rr.x + rr.y + rr.z + rr.w;
    psq  += rr.x * rr.x + rr.y * rr.y + rr.z * rr.z + rr.w * rr.w;
  }
#pragma unroll
  for (int d = 32; d > 0; d >>= 1) {
    psum += __shfl_down(psum, d);
    psq  += __shfl_down(psq, d);
  }
  __shared__ float rs_[4], rq_[4];
  int wid = t >> 6, lane = t & 63;
  if (lane == 0) { rs_[wid] = psum; rq_[wid] = psq; }
  __syncthreads();
  if (t == 0) {
    float a = 0.f, s2 = 0.f;
    for (int u = 0; u < 4; ++u) { a += rs_[u]; s2 += rq_[u]; }
    atomicAdd(&stats[b * 2],     a);
    atomicAdd(&stats[b * 2 + 1], s2);
  }
}

extern "C" void kernel_launch(void* const* d_in, const int* in_sizes, int n_in,
                              void* d_out, int out_size, void* d_ws, size_t ws_size,
                              hipStream_t stream) {
  const float* x   = (const float*)d_in[0];
  const float* ow1 = (const float*)d_in[1];
  const float* ob1 = (const float*)d_in[2];
  const float* dw1 = (const float*)d_in[3];
  const float* db1 = (const float*)d_in[4];
  const float* g1  = (const float*)d_in[5];
  const float* b1  = (const float*)d_in[6];
  const float* ow2 = (const float*)d_in[7];
  const float* ob2 = (const float*)d_in[8];
  const float* dw2 = (const float*)d_in[9];
  const float* db2 = (const float*)d_in[10];
  const float* g2  = (const float*)d_in[11];
  const float* b2  = (const float*)d_in[12];
  const float* g3  = (const float*)d_in[13];
  const float* b3  = (const float*)d_in[14];

  float* ws   = (float*)d_ws;
  float* off4 = ws;                                   // 4*B*18*HW = 1179648 f
  float* yb   = ws + 1179648;                         // B*C*HW    = 4194304 f
  float* hb   = ws + 1179648 + 4194304;               // B*C*HW
  float* st   = ws + 1179648 + 2 * 4194304;           // 32 f
  // wbf1/wbf2: 256*2304 bf16 = 589824 ushorts = 294912 floats EACH
  unsigned short* wbf1 = (unsigned short*)(ws + 9568288);
  unsigned short* wbf2 = (unsigned short*)(ws + 9568288 + 294912);
  float* outp = (float*)d_out;

  hipMemsetAsync(st, 0, 32 * sizeof(float), stream);
  cvt_bf16_k<<<576, 256, 0, stream>>>(dw1, wbf1, 147456);
  cvt_bf16_k<<<576, 256, 0, stream>>>(dw2, wbf2, 147456);

  // layer 1
  offset_conv_k<<<1024, 256, 0, stream>>>(x, ow1, ob1, off4);
  deform_mfma_k<<<512, 512, 0, stream>>>(x, off4, wbf1, db1, yb, st + 0);
  gn_k<<<2048, 256, 0, stream>>>(yb, st + 0, g1, b1, hb, 1);
  // layer 2
  offset_conv_k<<<1024, 256, 0, stream>>>(hb, ow2, ob2, off4);
  deform_mfma_k<<<512, 512, 0, stream>>>(hb, off4, wbf2, db2, yb, st + 8);
  gn_k<<<2048, 256, 0, stream>>>(yb, st + 8, g2, b2, hb, 1);
  // residual + final GN
  res_stats_k<<<1024, 256, 0, stream>>>(hb, x, yb, st + 16);
  gn_k<<<2048, 256, 0, stream>>>(yb, st + 16, g3, b3, outp, 0);
}

// Round 5
// 474.005 us; speedup vs baseline: 3.3269x; 1.2889x over previous
//
#include <hip/hip_runtime.h>
#include <hip/hip_fp16.h>

constexpr int B = 4, C = 256, H = 64, W = 64, HW = 4096;
constexpr int K2 = 9, OFFC = 18;
constexpr int SSTR = 296;           // bf16 elements per s_s row (592 B, 16B-aligned rows)

typedef short s16x8 __attribute__((ext_vector_type(8)));
typedef float f32x4 __attribute__((ext_vector_type(4)));

__device__ __forceinline__ unsigned short f2bf(float f) {
  unsigned u = __float_as_uint(f);
  u += 0x7fffu + ((u >> 16) & 1u);          // round-to-nearest-even
  return (unsigned short)(u >> 16);
}
__device__ __forceinline__ float bflo(unsigned q) { return __uint_as_float(q << 16); }
__device__ __forceinline__ float bfhi(unsigned q) { return __uint_as_float(q & 0xffff0000u); }

// ---------------- fp32 -> bf16 weight conversion, K reordered to cbi*288 + k*32 + c ----------------
__global__ void cvt_bf16_reord_k(const float* __restrict__ src, unsigned short* __restrict__ dst) {
  int idx = blockIdx.x * 256 + threadIdx.x;          // dst index, 256*2304 total
  if (idx >= 256 * 2304) return;
  int o = idx / 2304, kap = idx % 2304;
  int cbi = kap / 288, rem = kap % 288;
  int k = rem >> 5, c = rem & 31;
  dst[idx] = f2bf(src[((size_t)(o * 256 + cbi * 32 + c)) * 9 + k]);
}

// ---------------- offset conv partials: 3x3, 64 channels -> 18, pad 1 ----------------
__launch_bounds__(256)
__global__ void offset_conv_k(const float* __restrict__ x, const float* __restrict__ ow,
                              const float* __restrict__ ob, float* __restrict__ off4) {
  int cq = blockIdx.x & 3;
  int i  = (blockIdx.x >> 2) & 63;
  int b  = blockIdx.x >> 8;
  int t = threadIdx.x;
  int j = t & 63;
  int ocg = __builtin_amdgcn_readfirstlane(t >> 6);   // wave-uniform 0..3
  __shared__ float xs[32][3][66];
  const float* xb = x + (size_t)b * C * HW;

  if (t < 96) { int cc = t & 31, rr = t >> 5; xs[cc][rr][0] = 0.f; xs[cc][rr][65] = 0.f; }

  float acc[5];
#pragma unroll
  for (int s = 0; s < 5; ++s) {
    int oc = ocg + 4 * s;
    acc[s] = (cq == 0 && oc < OFFC) ? ob[oc] : 0.f;
  }

  for (int half = 0; half < 2; ++half) {
    int cbase = cq * 64 + half * 32;
    for (int idx = t; idx < 32 * 192; idx += 256) {
      int cc = idx / 192, rem = idx - cc * 192;
      int rr = rem >> 6, j2 = rem & 63;
      int yy = i + rr - 1;
      xs[cc][rr][1 + j2] = (yy >= 0 && yy < H) ? xb[(size_t)(cbase + cc) * HW + yy * 64 + j2] : 0.f;
    }
    __syncthreads();
    for (int cc = 0; cc < 32; ++cc) {
      float xv[9];
#pragma unroll
      for (int rr = 0; rr < 3; ++rr)
#pragma unroll
        for (int dxx = 0; dxx < 3; ++dxx) xv[rr * 3 + dxx] = xs[cc][rr][j + dxx];
#pragma unroll
      for (int s = 0; s < 5; ++s) {
        int oc = ocg + 4 * s;
        if (oc < OFFC) {
          const float* wp = ow + ((size_t)oc * C + cbase + cc) * 9;   // uniform -> s_load
#pragma unroll
          for (int k = 0; k < 9; ++k) acc[s] += xv[k] * wp[k];
        }
      }
    }
    __syncthreads();
  }
#pragma unroll
  for (int s = 0; s < 5; ++s) {
    int oc = ocg + 4 * s;
    if (oc < OFFC)
      off4[(((size_t)(cq * B + b) * OFFC + oc) << 12) + (i << 6) + j] = acc[s];
  }
}

// ---------------- fused deformable conv (bf16 MFMA, LDS patch gather) ----------------
// block = (b, i, half-row): GEMM out[32 px][256 o] = sampled[32][2304] x W^T
__launch_bounds__(512, 4)
__global__ void deform_mfma_k(const float* __restrict__ xin, const float* __restrict__ off4,
                              const unsigned short* __restrict__ wbf,
                              const float* __restrict__ bias,
                              float* __restrict__ y, float* __restrict__ stats) {
  int jh = blockIdx.x & 1;
  int i  = (blockIdx.x >> 1) & 63;
  int b  = blockIdx.x >> 7;
  int t = threadIdx.x;
  int lane = t & 63, wv = t >> 6;        // 8 waves
  int cidx = lane & 15, r = lane >> 4;   // MFMA lane decomposition
  int jl = t & 31, cg = t >> 5;          // gather/patch mapping: pixel jl, channel-pair cg

  // LDS: metadata 4.6K + patch dbuf 45K + sampled tile 18.9K = ~68.7 KB -> 2 blocks/CU
  __shared__ __align__(16) unsigned s_md[K2][32][4];
  __shared__ __align__(16) unsigned short s_pt[2][11264];   // [16 pairs][8 rows][44 cols][2ch]
  __shared__ __align__(16) unsigned short s_s[32][SSTR];
  __shared__ float rs_[8], rq_[8];

  const float* xb = xin + (size_t)b * C * HW;
  int br = i - 3, bc = (jh << 5) - 5;     // patch origin (rows br..br+7, cols bc..bc+43)

  // patch load offsets (constant per thread across chunks)
  int gof[11], wof[11];
#pragma unroll
  for (int e = 0; e < 11; ++e) {
    int pos = jl + (e << 5);
    int row = pos / 44, col = pos - row * 44;
    int rr = min(max(br + row, 0), H - 1);
    int c2 = min(max(bc + col, 0), W - 1);
    gof[e] = rr * 64 + c2;
    wof[e] = cg * 704 + row * 88 + col * 2;
  }

  // prologue: issue patch-0 global loads
  float l0[11], l1[11];
  {
    const float* bp = xb + (size_t)(cg * 2) * HW;
#pragma unroll
    for (int e = 0; e < 11; ++e) { l0[e] = bp[gof[e]]; l1[e] = bp[HW + gof[e]]; }
  }

  // Phase A: metadata (9 taps x 32 px), patch-relative + rare-fallback info
  for (int idx = t; idx < K2 * 32; idx += 512) {
    int k = idx >> 5, jj = idx & 31;
    int j = (jh << 5) + jj;
    float dy = 0.f, dx = 0.f;
#pragma unroll
    for (int cq = 0; cq < 4; ++cq) {
      const float* p = off4 + (((size_t)(cq * B + b) * OFFC) << 12) + (i << 6) + j;
      dy += p[(2 * k) << 12];
      dx += p[(2 * k + 1) << 12];
    }
    float py = (float)(i + (k / 3) - 1) + dy;
    float px = (float)(j + (k % 3) - 1) + dx;
    float y0f = floorf(py), x0f = floorf(px);
    float wy1 = py - y0f, wx1 = px - x0f;
    float wy0 = 1.f - wy1, wx0 = 1.f - wx1;
    int y0 = (int)y0f, x0 = (int)x0f;
    if (y0 < 0 || y0 >= H)         wy0 = 0.f;
    if (y0 + 1 < 0 || y0 + 1 >= H) wy1 = 0.f;
    if (x0 < 0 || x0 >= W)         wx0 = 0.f;
    if (x0 + 1 < 0 || x0 + 1 >= W) wx1 = 0.f;
    int y0c = min(max(y0, 0), H - 1), y1c = min(max(y0 + 1, 0), H - 1);
    int x0c = min(max(x0, 0), W - 1), x1c = min(max(x0 + 1, 0), W - 1);
    int dys = y1c - y0c, dxs = x1c - x0c;
    unsigned p0 = (unsigned)__half_as_ushort(__float2half_rn(wy0 * wx0)) |
                  ((unsigned)__half_as_ushort(__float2half_rn(wy0 * wx1)) << 16);
    unsigned p1 = (unsigned)__half_as_ushort(__float2half_rn(wy1 * wx0)) |
                  ((unsigned)__half_as_ushort(__float2half_rn(wy1 * wx1)) << 16);
    bool ip = (y0c >= br) && (y1c <= br + 7) && (x0c >= bc) && (x1c <= bc + 43);
    unsigned pb = (unsigned)((y0c - br) * 88 + (x0c - bc) * 2);
    unsigned p2 = (ip ? (pb & 0xfff) : 0u) | ((unsigned)dxs << 12) | ((unsigned)dys << 13) |
                  (ip ? 0u : 0x4000u);
    unsigned p3 = (unsigned)(y0c * 64 + x0c) | ((unsigned)dxs << 12) | ((unsigned)dys << 13);
    *reinterpret_cast<uint4*>(&s_md[k][jj][0]) = make_uint4(p0, p1, p2, p3);
  }

  // write patch 0
#pragma unroll
  for (int e = 0; e < 11; ++e)
    *reinterpret_cast<unsigned*>(&s_pt[0][wof[e]]) =
        (unsigned)f2bf(l0[e]) | ((unsigned)f2bf(l1[e]) << 16);
  __syncthreads();

  f32x4 acc[2][2];
#pragma unroll
  for (int m = 0; m < 2; ++m) {
    acc[m][0] = {0.f, 0.f, 0.f, 0.f};
    acc[m][1] = {0.f, 0.f, 0.f, 0.f};
  }
  int ob_ = wv * 32;
  const unsigned short* w0p = wbf + (size_t)(ob_ + cidx) * 2304;
  const unsigned short* w1p = w0p + 16 * 2304;

  for (int cb = 0; cb < 8; ++cb) {
    int cur = cb & 1;
    // issue next patch loads (latency hidden under gather+interp)
    if (cb < 7) {
      const float* bp = xb + (size_t)((cb + 1) * 32 + cg * 2) * HW;
#pragma unroll
      for (int e = 0; e < 11; ++e) { l0[e] = bp[gof[e]]; l1[e] = bp[HW + gof[e]]; }
    }
    // gather from patch + interp -> s_s  (pixel jl, channels 2cg,2cg+1)
    {
      const unsigned short* pt = &s_pt[cur][cg * 704];
#pragma unroll
      for (int k = 0; k < K2; ++k) {
        uint4 m = *reinterpret_cast<const uint4*>(&s_md[k][jl][0]);
        float w00 = __half2float(__ushort_as_half((unsigned short)(m.x & 0xffff)));
        float w01 = __half2float(__ushort_as_half((unsigned short)(m.x >> 16)));
        float w10 = __half2float(__ushort_as_half((unsigned short)(m.y & 0xffff)));
        float w11 = __half2float(__ushort_as_half((unsigned short)(m.y >> 16)));
        int pb = m.z & 0xfff;
        int dx2 = ((m.z >> 12) & 1) * 2, dy88 = ((m.z >> 13) & 1) * 88;
        unsigned q00 = *reinterpret_cast<const unsigned*>(pt + pb);
        unsigned q01 = *reinterpret_cast<const unsigned*>(pt + pb + dx2);
        unsigned q10 = *reinterpret_cast<const unsigned*>(pt + pb + dy88);
        unsigned q11 = *reinterpret_cast<const unsigned*>(pt + pb + dy88 + dx2);
        float v0 = w00 * bflo(q00) + w01 * bflo(q01) + w10 * bflo(q10) + w11 * bflo(q11);
        float v1 = w00 * bfhi(q00) + w01 * bfhi(q01) + w10 * bfhi(q10) + w11 * bfhi(q11);
        if (m.z & 0x4000u) {                       // rare: clamped corners escape patch
          int i00 = m.w & 0xfff;
          int fdx = (m.w >> 12) & 1, fdy = ((m.w >> 13) & 1) * 64;
          const float* xc0 = xb + (size_t)(cb * 32 + cg * 2) * HW;
          const float* xc1 = xc0 + HW;
          v0 = w00 * xc0[i00] + w01 * xc0[i00 + fdx] + w10 * xc0[i00 + fdy] + w11 * xc0[i00 + fdy + fdx];
          v1 = w00 * xc1[i00] + w01 * xc1[i00 + fdx] + w10 * xc1[i00 + fdy] + w11 * xc1[i00 + fdy + fdx];
        }
        *reinterpret_cast<unsigned*>(&s_s[jl][k * 32 + cg * 2]) =
            (unsigned)f2bf(v0) | ((unsigned)f2bf(v1) << 16);
      }
    }
    // write next patch (vmcnt drained naturally; writes other buffer)
    if (cb < 7) {
#pragma unroll
      for (int e = 0; e < 11; ++e)
        *reinterpret_cast<unsigned*>(&s_pt[cur ^ 1][wof[e]]) =
            (unsigned)f2bf(l0[e]) | ((unsigned)f2bf(l1[e]) << 16);
    }
    __syncthreads();
    // MFMA phase: K-steps = 9 taps (K=32 each: tap k x 32 channels)
    int kb0 = cb * 288 + r * 8;
#pragma unroll 3
    for (int kk = 0; kk < 9; ++kk) {
      int kl = kk * 32 + r * 8;
      s16x8 a0 = *(const s16x8*)&s_s[cidx][kl];
      s16x8 a1 = *(const s16x8*)&s_s[16 + cidx][kl];
      s16x8 b0 = *(const s16x8*)&w0p[kb0 + kk * 32];
      s16x8 b1 = *(const s16x8*)&w1p[kb0 + kk * 32];
      acc[0][0] = __builtin_amdgcn_mfma_f32_16x16x32_bf16(a0, b0, acc[0][0], 0, 0, 0);
      acc[1][0] = __builtin_amdgcn_mfma_f32_16x16x32_bf16(a1, b0, acc[1][0], 0, 0, 0);
      acc[0][1] = __builtin_amdgcn_mfma_f32_16x16x32_bf16(a0, b1, acc[0][1], 0, 0, 0);
      acc[1][1] = __builtin_amdgcn_mfma_f32_16x16x32_bf16(a1, b1, acc[1][1], 0, 0, 0);
    }
    __syncthreads();
  }

  // epilogue: bias, store, GN partial stats
  float bv0 = bias[ob_ + cidx], bv1 = bias[ob_ + 16 + cidx];
  float psum = 0.f, psq = 0.f;
#pragma unroll
  for (int m = 0; m < 2; ++m) {
#pragma unroll
    for (int n = 0; n < 2; ++n) {
      int o = ob_ + n * 16 + cidx;
      float bv = n ? bv1 : bv0;
      float4 vv;
      vv.x = acc[m][n][0] + bv; vv.y = acc[m][n][1] + bv;
      vv.z = acc[m][n][2] + bv; vv.w = acc[m][n][3] + bv;
      *reinterpret_cast<float4*>(y + (((size_t)(b * C + o)) << 12) + (i << 6) + (jh << 5) + m * 16 + r * 4) = vv;
      psum += vv.x + vv.y + vv.z + vv.w;
      psq  += vv.x * vv.x + vv.y * vv.y + vv.z * vv.z + vv.w * vv.w;
    }
  }
#pragma unroll
  for (int d = 32; d > 0; d >>= 1) {
    psum += __shfl_down(psum, d);
    psq  += __shfl_down(psq, d);
  }
  if (lane == 0) { rs_[wv] = psum; rq_[wv] = psq; }
  __syncthreads();
  if (t == 0) {
    float a = 0.f, s2 = 0.f;
    for (int u = 0; u < 8; ++u) { a += rs_[u]; s2 += rq_[u]; }
    atomicAdd(&stats[b * 2],     a);
    atomicAdd(&stats[b * 2 + 1], s2);
  }
}

// ---------------- group-norm (per-sample over C,H,W) + optional relu ----------------
__global__ void gn_k(const float* __restrict__ yv, const float* __restrict__ stats,
                     const float* __restrict__ g, const float* __restrict__ be,
                     float* __restrict__ outp, int relu) {
  const float inv = 1.f / (float)(C * HW);
  int stride = gridDim.x * blockDim.x;
  int total4 = B * C * HW / 4;
  for (int idx = blockIdx.x * blockDim.x + threadIdx.x; idx < total4; idx += stride) {
    int e = idx << 2;
    int b = e >> 20;
    int c = (e >> 12) & 255;
    float mean = stats[b * 2] * inv;
    float var  = stats[b * 2 + 1] * inv - mean * mean;
    float rs   = rsqrtf(var + 1e-5f);
    float a  = g[c] * rs;
    float b2 = be[c] - mean * a;
    float4 v = *reinterpret_cast<const float4*>(yv + e);
    float4 rr;
    rr.x = v.x * a + b2; rr.y = v.y * a + b2; rr.z = v.z * a + b2; rr.w = v.w * a + b2;
    if (relu) {
      rr.x = fmaxf(0.f, rr.x); rr.y = fmaxf(0.f, rr.y);
      rr.z = fmaxf(0.f, rr.z); rr.w = fmaxf(0.f, rr.w);
    }
    *reinterpret_cast<float4*>(outp + e) = rr;
  }
}

// ---------------- residual add + GN partial stats ----------------
__global__ void res_stats_k(const float* __restrict__ h2, const float* __restrict__ x,
                            float* __restrict__ z, float* __restrict__ stats) {
  int b = blockIdx.x >> 8;
  int seg = blockIdx.x & 255;
  size_t base = ((size_t)b << 20) + ((size_t)seg << 12);
  int t = threadIdx.x;
  float psum = 0.f, psq = 0.f;
#pragma unroll
  for (int u = 0; u < 4; ++u) {
    size_t e = base + (size_t)(u * 256 + t) * 4;
    float4 a = *reinterpret_cast<const float4*>(h2 + e);
    float4 c = *reinterpret_cast<const float4*>(x + e);
    float4 rr = make_float4(a.x + c.x, a.y + c.y, a.z + c.z, a.w + c.w);
    *reinterpret_cast<float4*>(z + e) = rr;
    psum += rr.x + rr.y + rr.z + rr.w;
    psq  += rr.x * rr.x + rr.y * rr.y + rr.z * rr.z + rr.w * rr.w;
  }
#pragma unroll
  for (int d = 32; d > 0; d >>= 1) {
    psum += __shfl_down(psum, d);
    psq  += __shfl_down(psq, d);
  }
  __shared__ float rs_[4], rq_[4];
  int wid = t >> 6, lane = t & 63;
  if (lane == 0) { rs_[wid] = psum; rq_[wid] = psq; }
  __syncthreads();
  if (t == 0) {
    float a = 0.f, s2 = 0.f;
    for (int u = 0; u < 4; ++u) { a += rs_[u]; s2 += rq_[u]; }
    atomicAdd(&stats[b * 2],     a);
    atomicAdd(&stats[b * 2 + 1], s2);
  }
}

extern "C" void kernel_launch(void* const* d_in, const int* in_sizes, int n_in,
                              void* d_out, int out_size, void* d_ws, size_t ws_size,
                              hipStream_t stream) {
  const float* x   = (const float*)d_in[0];
  const float* ow1 = (const float*)d_in[1];
  const float* ob1 = (const float*)d_in[2];
  const float* dw1 = (const float*)d_in[3];
  const float* db1 = (const float*)d_in[4];
  const float* g1  = (const float*)d_in[5];
  const float* b1  = (const float*)d_in[6];
  const float* ow2 = (const float*)d_in[7];
  const float* ob2 = (const float*)d_in[8];
  const float* dw2 = (const float*)d_in[9];
  const float* db2 = (const float*)d_in[10];
  const float* g2  = (const float*)d_in[11];
  const float* b2  = (const float*)d_in[12];
  const float* g3  = (const float*)d_in[13];
  const float* b3  = (const float*)d_in[14];

  float* ws   = (float*)d_ws;
  float* off4 = ws;                                   // 4*B*18*HW = 1179648 f
  float* yb   = ws + 1179648;                         // B*C*HW    = 4194304 f
  float* hb   = ws + 1179648 + 4194304;               // B*C*HW
  float* st   = ws + 1179648 + 2 * 4194304;           // 32 f
  // wbf1/wbf2: 256*2304 bf16 = 589824 ushorts = 294912 floats EACH
  unsigned short* wbf1 = (unsigned short*)(ws + 9568288);
  unsigned short* wbf2 = (unsigned short*)(ws + 9568288 + 294912);
  float* outp = (float*)d_out;

  hipMemsetAsync(st, 0, 32 * sizeof(float), stream);
  cvt_bf16_reord_k<<<2304, 256, 0, stream>>>(dw1, wbf1);
  cvt_bf16_reord_k<<<2304, 256, 0, stream>>>(dw2, wbf2);

  // layer 1
  offset_conv_k<<<1024, 256, 0, stream>>>(x, ow1, ob1, off4);
  deform_mfma_k<<<512, 512, 0, stream>>>(x, off4, wbf1, db1, yb, st + 0);
  gn_k<<<2048, 256, 0, stream>>>(yb, st + 0, g1, b1, hb, 1);
  // layer 2
  offset_conv_k<<<1024, 256, 0, stream>>>(hb, ow2, ob2, off4);
  deform_mfma_k<<<512, 512, 0, stream>>>(hb, off4, wbf2, db2, yb, st + 8);
  gn_k<<<2048, 256, 0, stream>>>(yb, st + 8, g2, b2, hb, 1);
  // residual + final GN
  res_stats_k<<<1024, 256, 0, stream>>>(hb, x, yb, st + 16);
  gn_k<<<2048, 256, 0, stream>>>(yb, st + 16, g3, b3, outp, 0);
}